// Round 3
// baseline (302.565 us; speedup 1.0000x reference)
//
#include <hip/hip_runtime.h>
#include <hip/hip_bf16.h>

// Embedding gather: out[i, :] = embeddings[X[i], :]
// X: 32768 int32 indices; embeddings: 50257 x 1024 fp32 (row = 256 x 16B = 4 KiB).
//
// 8 rows per block, fully unrolled: 8 independent index s_loads + 8
// independent 16B/lane gathers in flight per wave (MLP=8) instead of a
// single serial chain. Nontemporal stores keep the 128 MB output stream
// from evicting the ~100 MB hot embedding table out of L2/L3.
//
// NOTE: __builtin_nontemporal_store requires a clang native vector type,
// not HIP's HIP_vector_type<float,4> struct -> use ext_vector_type(4).

typedef float vfloat4 __attribute__((ext_vector_type(4)));

constexpr int RPB = 8;  // rows per block

__global__ __launch_bounds__(256) void embedding_gather_kernel(
    const int* __restrict__ X,
    const vfloat4* __restrict__ emb,   // row stride = 256 vfloat4
    vfloat4* __restrict__ out,
    int n_rows)
{
    const int col4 = threadIdx.x;          // 256 x 16B per row
    const int row0 = blockIdx.x * RPB;

    if (row0 + RPB <= n_rows) {
        int idx[RPB];
        #pragma unroll
        for (int k = 0; k < RPB; ++k)
            idx[k] = X[row0 + k];          // wave-uniform -> s_load, 8 in flight

        vfloat4 v[RPB];
        #pragma unroll
        for (int k = 0; k < RPB; ++k)      // 8 independent 16B/lane gathers
            v[k] = emb[(size_t)idx[k] * 256 + col4];

        #pragma unroll
        for (int k = 0; k < RPB; ++k)      // streaming stores, skip cache
            __builtin_nontemporal_store(v[k], &out[(size_t)(row0 + k) * 256 + col4]);
    } else {
        for (int r = row0; r < n_rows; ++r) {
            const int idx = X[r];
            vfloat4 v = emb[(size_t)idx * 256 + col4];
            __builtin_nontemporal_store(v, &out[(size_t)r * 256 + col4]);
        }
    }
}

extern "C" void kernel_launch(void* const* d_in, const int* in_sizes, int n_in,
                              void* d_out, int out_size, void* d_ws, size_t ws_size,
                              hipStream_t stream) {
    const int*     X   = (const int*)d_in[0];
    const vfloat4* emb = (const vfloat4*)d_in[1];
    vfloat4*       out = (vfloat4*)d_out;
    const int n_rows = in_sizes[0];        // 32768
    const int grid   = (n_rows + RPB - 1) / RPB;   // 4096 blocks
    embedding_gather_kernel<<<grid, 256, 0, stream>>>(X, emb, out, n_rows);
}